// Round 1
// baseline (192.881 us; speedup 1.0000x reference)
//
#include <hip/hip_runtime.h>
#include <hip/hip_bf16.h>
#include <stdint.h>

#define HIDDEN 1024
#define NHEADS 16
#define DHEAD  64
#define BATCH  2
#define SEQ    2048
#define MROWS  (BATCH*SEQ)   // 4096
#define QKVC   (3*HIDDEN)    // 3072

typedef unsigned short u16;
typedef unsigned int   u32;
typedef __bf16 bf16x8 __attribute__((ext_vector_type(8)));
typedef float  f32x4  __attribute__((ext_vector_type(4)));
typedef short  s16x4  __attribute__((ext_vector_type(4)));
typedef u16    u16x8  __attribute__((ext_vector_type(8)));

typedef const __attribute__((address_space(1))) void gvoid_t;
typedef       __attribute__((address_space(3))) void lvoid_t;

// generic->AS(1): global generic pointer value == global address
__device__ __forceinline__ gvoid_t* to_glob(const void* p){
  return (gvoid_t*)(uintptr_t)p;
}
// generic->AS(3): LDS aperture is 2^32-aligned, low 32 bits == LDS byte offset
__device__ __forceinline__ lvoid_t* to_lds(void* p){
  return (lvoid_t*)(uintptr_t)p;
}
__device__ __forceinline__ u32 lds_off(const void* p){
  return (u32)(uintptr_t)p;
}

__device__ __forceinline__ u16 f2bf(float x){   // RNE f32->bf16
  u32 u = __builtin_bit_cast(u32, x);
  u32 r = (u + 0x7fffu + ((u >> 16) & 1u)) >> 16;
  return (u16)r;
}

// ---------------- fp32 -> bf16 conversion ----------------
__global__ __launch_bounds__(256) void k_cvt(const float* __restrict__ in,
                                             u16* __restrict__ out, int n4){
  int i = blockIdx.x * 256 + threadIdx.x;
  if (i >= n4) return;
  const float4 v = reinterpret_cast<const float4*>(in)[i];
  ushort4 o;
  o.x = f2bf(v.x); o.y = f2bf(v.y); o.z = f2bf(v.z); o.w = f2bf(v.w);
  reinterpret_cast<ushort4*>(out)[i] = o;
}

// ---------------- bf16 GEMM, C = A * B^T + bias ----------------
// A [4096][1024] bf16, B [NC][1024] bf16 (both K-major). 128x128 tile, BK=32,
// 4 waves (2x2), 4x4 16x16x32 fragments per wave. m97-style global_load_lds staging.
template<int NC, bool BF16OUT>
__global__ __launch_bounds__(256) void k_gemm(const u16* __restrict__ A,
                                              const u16* __restrict__ B,
                                              const float* __restrict__ bias,
                                              void* __restrict__ C){
  constexpr int K = HIDDEN;
  __shared__ u16 As[128*32];
  __shared__ u16 Bs[128*32];
  const int m0 = blockIdx.x * 128;
  const int n0 = blockIdx.y * 128;
  const int tid = threadIdx.x;
  const int w = tid >> 6, l = tid & 63;
  const int wr = w >> 1, wc = w & 1;

  const f32x4 fz = {0.f, 0.f, 0.f, 0.f};
  f32x4 acc[4][4];
  #pragma unroll
  for (int i = 0; i < 4; ++i)
    #pragma unroll
    for (int j = 0; j < 4; ++j) acc[i][j] = fz;

  // staging: lane i covers tile row i/4, k-chunk (i%4)*8 (issue0 rows 0..63, issue1 64..127)
  const u16* ap = A + (size_t)(m0 + (tid >> 2)) * K + (tid & 3) * 8;
  const u16* bp = B + (size_t)(n0 + (tid >> 2)) * K + (tid & 3) * 8;

  for (int k0 = 0; k0 < K; k0 += 32){
    __syncthreads();   // previous iteration's LDS reads done (compiler drains lgkm)
    __builtin_amdgcn_global_load_lds(to_glob(ap + k0),          to_lds(&As[w*512]),        16, 0, 0);
    __builtin_amdgcn_global_load_lds(to_glob(ap + 64*K + k0),   to_lds(&As[2048 + w*512]), 16, 0, 0);
    __builtin_amdgcn_global_load_lds(to_glob(bp + k0),          to_lds(&Bs[w*512]),        16, 0, 0);
    __builtin_amdgcn_global_load_lds(to_glob(bp + 64*K + k0),   to_lds(&Bs[2048 + w*512]), 16, 0, 0);
    __syncthreads();   // compiler emits vmcnt(0) before barrier -> tiles ready

    bf16x8 af[4], bfr[4];
    #pragma unroll
    for (int mf = 0; mf < 4; ++mf)
      af[mf]  = *(const bf16x8*)&As[(wr*64 + mf*16 + (l & 15))*32 + (l >> 4)*8];
    #pragma unroll
    for (int nf = 0; nf < 4; ++nf)
      bfr[nf] = *(const bf16x8*)&Bs[(wc*64 + nf*16 + (l & 15))*32 + (l >> 4)*8];
    #pragma unroll
    for (int mf = 0; mf < 4; ++mf)
      #pragma unroll
      for (int nf = 0; nf < 4; ++nf)
        acc[mf][nf] = __builtin_amdgcn_mfma_f32_16x16x32_bf16(af[mf], bfr[nf], acc[mf][nf], 0, 0, 0);
  }

  // epilogue: D row = (l>>4)*4+r, col = l&15 (m89-verified C/D layout)
  #pragma unroll
  for (int nf = 0; nf < 4; ++nf){
    const int col = n0 + wc*64 + nf*16 + (l & 15);
    const float bv = bias[col];
    #pragma unroll
    for (int mf = 0; mf < 4; ++mf){
      #pragma unroll
      for (int r = 0; r < 4; ++r){
        const int row = m0 + wr*64 + mf*16 + (l >> 4)*4 + r;
        const float v = acc[mf][nf][r] + bv;
        if constexpr (BF16OUT) ((u16*)C)[(size_t)row * NC + col] = f2bf(v);
        else                   ((float*)C)[(size_t)row * NC + col] = v;
      }
    }
  }
}

// ---------------- causal flash attention ----------------
// grid = (SEQ/64, BATCH*NHEADS); block = 256 (4 waves, 16 q-rows per wave).
// qkv layout per token row (3072): head h -> [h*192 + 0:64]=Q, [+64:128]=K, [+128:192]=V
__global__ __launch_bounds__(256) void k_attn(const u16* __restrict__ qkv,
                                              u16* __restrict__ aout){
  __shared__ u16 Ks[64*64];      // [k][d], chunk-XOR swizzled (see staging)
  __shared__ u16 Vs[64*64];      // subtiled layout for ds_read_b64_tr_b16
  __shared__ u16 Ps[4*16*72];    // per-wave P round-trip, padded stride 72

  const int qt = blockIdx.x;
  const int b  = blockIdx.y >> 4;
  const int h  = blockIdx.y & 15;
  const int tid = threadIdx.x;
  const int w = tid >> 6, l = tid & 63;
  const int q0 = qt * 64;
  const size_t base = (size_t)b * SEQ * QKVC + (size_t)h * 192;

  // Q fragments in registers: A[row=q(l&15)][d=(l>>4)*8 + kk*32 + j]
  bf16x8 qf[2];
  {
    const u16* qp = qkv + base + (size_t)(q0 + w*16 + (l & 15)) * QKVC + (l >> 4) * 8;
    qf[0] = *(const bf16x8*)(qp);
    qf[1] = *(const bf16x8*)(qp + 32);
  }

  const f32x4 fz = {0.f, 0.f, 0.f, 0.f};
  f32x4 o[4];
  float mrun[4], lrun[4];
  #pragma unroll
  for (int i = 0; i < 4; ++i){ o[i] = fz; mrun[i] = -1e30f; lrun[i] = 0.f; }

  const u32 vs_base = lds_off(Vs) + l * 8;

  for (int kt = 0; kt <= qt; ++kt){
    __syncthreads();   // previous tile's reads (incl. asm tr-reads, which self-drain) done

    // ---- stage K via global_load_lds; LDS linear, global source chunk-XOR pre-swizzled
    // reader uses chunk' = chunk ^ (row&7)  ->  even bank spread for ds_read_b128
    #pragma unroll
    for (int t = 0; t < 2; ++t){
      const int i  = t*256 + tid;
      const int kr = i >> 3;
      const int cg = (i & 7) ^ (kr & 7);
      const u16* src = qkv + base + (size_t)(kt*64 + kr) * QKVC + 64 + cg * 8;
      __builtin_amdgcn_global_load_lds(to_glob(src), to_lds(&Ks[t*2048 + w*512]), 16, 0, 0);
    }

    // ---- stage V (reg-staged) into tr-read subtile layout:
    // flat(k,d) = (k>>5)<<11 | (d>>4)<<9 | ((k>>2)&1)<<8 | ((k>>3)&3)<<6 | (k&3)<<4 | (d&15)
    u16x8 vt[2];
    #pragma unroll
    for (int t = 0; t < 2; ++t){
      const int i = t*256 + tid;
      const int k = i >> 3, d0 = (i & 7) * 8;
      vt[t] = *(const u16x8*)(qkv + base + (size_t)(kt*64 + k) * QKVC + 128 + d0);
    }
    #pragma unroll
    for (int t = 0; t < 2; ++t){
      const int i = t*256 + tid;
      const int k = i >> 3, d0 = (i & 7) * 8;
      const int flat = ((k >> 5) << 11) + ((d0 >> 4) << 9) + (((k >> 2) & 1) << 8)
                     + (((k >> 3) & 3) << 6) + ((k & 3) << 4) + (d0 & 15);
      *(u16x8*)&Vs[flat] = vt[t];
    }
    __syncthreads();

    // ---- S = (Q K^T) * 1/8 ; B-frag = K rows read k-contiguous
    f32x4 s[4];
    #pragma unroll
    for (int nf = 0; nf < 4; ++nf){
      const int row = nf*16 + (l & 15);
      const int sw  = row & 7;
      const bf16x8 kf0 = *(const bf16x8*)&Ks[row*64 + (((l >> 4)    ) ^ sw) * 8];
      const bf16x8 kf1 = *(const bf16x8*)&Ks[row*64 + (((l >> 4) + 4) ^ sw) * 8];
      f32x4 a = fz;
      a = __builtin_amdgcn_mfma_f32_16x16x32_bf16(qf[0], kf0, a, 0, 0, 0);
      a = __builtin_amdgcn_mfma_f32_16x16x32_bf16(qf[1], kf1, a, 0, 0, 0);
      s[nf] = a;
    }

    // ---- scale, causal mask (diagonal tile only), row-max
    const bool diag = (kt == qt);
    float rmax[4] = {-1e30f, -1e30f, -1e30f, -1e30f};
    #pragma unroll
    for (int nf = 0; nf < 4; ++nf){
      #pragma unroll
      for (int r = 0; r < 4; ++r){
        float v = s[nf][r] * 0.125f;
        if (diag){
          const int qg = w*16 + ((l >> 4) << 2) + r;  // local indices, q0 == kt*64
          const int kg = nf*16 + (l & 15);
          if (kg > qg) v = -1e30f;
        }
        s[nf][r] = v;
        rmax[r] = fmaxf(rmax[r], v);
      }
    }
    #pragma unroll
    for (int r = 0; r < 4; ++r){
      #pragma unroll
      for (int msk = 1; msk < 16; msk <<= 1)
        rmax[r] = fmaxf(rmax[r], __shfl_xor(rmax[r], msk));
    }

    // ---- online softmax update
    float corr[4], psum[4];
    #pragma unroll
    for (int r = 0; r < 4; ++r){
      const float mn = fmaxf(mrun[r], rmax[r]);
      corr[r] = __expf(mrun[r] - mn);
      mrun[r] = mn;
      psum[r] = 0.f;
    }
    #pragma unroll
    for (int nf = 0; nf < 4; ++nf){
      #pragma unroll
      for (int r = 0; r < 4; ++r){
        const float p = __expf(s[nf][r] - mrun[r]);
        psum[r] += p;
        Ps[(w*16 + ((l >> 4) << 2) + r)*72 + nf*16 + (l & 15)] = f2bf(p);
      }
    }
    #pragma unroll
    for (int r = 0; r < 4; ++r){
      #pragma unroll
      for (int msk = 1; msk < 16; msk <<= 1)
        psum[r] += __shfl_xor(psum[r], msk);
      lrun[r] = lrun[r] * corr[r] + psum[r];
    }
    #pragma unroll
    for (int nf = 0; nf < 4; ++nf)
      #pragma unroll
      for (int r = 0; r < 4; ++r)
        o[nf][r] *= corr[r];

    // ---- PV: A = P (from Ps, k-contiguous), B = V via ds_read_b64_tr_b16
    #pragma unroll
    for (int kk = 0; kk < 2; ++kk){
      const bf16x8 pa = *(const bf16x8*)&Ps[(w*16 + (l & 15))*72 + kk*32 + (l >> 4)*8];
      #pragma unroll
      for (int nf = 0; nf < 4; ++nf){
        s16x4 lo, hi;
        const u32 va = vs_base + kk*4096 + nf*1024;
        // lane l, elem j <- Vs_elems[base/2 + (l>>4)*64 + j*16 + (l&15)]  (m156/m162)
        asm volatile("ds_read_b64_tr_b16 %0, %2 offset:0\n\t"
                     "ds_read_b64_tr_b16 %1, %2 offset:512\n\t"
                     "s_waitcnt lgkmcnt(0)"
                     : "=v"(lo), "=v"(hi) : "v"(va) : "memory");
        union { s16x4 hh[2]; bf16x8 v; } cv;
        cv.hh[0] = lo; cv.hh[1] = hi;
        o[nf] = __builtin_amdgcn_mfma_f32_16x16x32_bf16(pa, cv.v, o[nf], 0, 0, 0);
      }
    }
  }

  // ---- epilogue: normalize, write bf16 [token][h*64+d]
  #pragma unroll
  for (int r = 0; r < 4; ++r){
    const float inv = 1.0f / lrun[r];
    const int qg = q0 + w*16 + ((l >> 4) << 2) + r;
    u16* op = aout + (size_t)(b*SEQ + qg) * HIDDEN + h*64 + (l & 15);
    #pragma unroll
    for (int nf = 0; nf < 4; ++nf)
      op[nf*16] = f2bf(o[nf][r] * inv);
  }
}

// ---------------- launch ----------------
extern "C" void kernel_launch(void* const* d_in, const int* in_sizes, int n_in,
                              void* d_out, int out_size, void* d_ws, size_t ws_size,
                              hipStream_t stream){
  const float* enc    = (const float*)d_in[0];
  const float* attn_w = (const float*)d_in[1];
  const float* attn_b = (const float*)d_in[2];
  const float* out_w  = (const float*)d_in[3];
  const float* out_b  = (const float*)d_in[4];

  char* ws = (char*)d_ws;
  // ws layout (40 MiB total):
  //   [0,8M)   enc_bf16     (reused as attn-out bf16 after GEMM1 consumed it)
  //   [8,14M)  attn_w bf16
  //   [14,16M) out_w bf16
  //   [16,40M) qkv bf16 [4096][3072]
  u16* enc_bf = (u16*)(ws);
  u16* wa_bf  = (u16*)(ws + (size_t)( 8u << 20));
  u16* wo_bf  = (u16*)(ws + (size_t)(14u << 20));
  u16* qkv    = (u16*)(ws + (size_t)(16u << 20));
  u16* aout   = enc_bf;  // safe alias: attn runs strictly after GEMM1

  k_cvt<<<dim3((MROWS*HIDDEN/4 + 255)/256), 256, 0, stream>>>(enc,    enc_bf, MROWS*HIDDEN/4);
  k_cvt<<<dim3((QKVC*HIDDEN/4  + 255)/256), 256, 0, stream>>>(attn_w, wa_bf,  QKVC*HIDDEN/4);
  k_cvt<<<dim3((HIDDEN*HIDDEN/4+ 255)/256), 256, 0, stream>>>(out_w,  wo_bf,  HIDDEN*HIDDEN/4);

  k_gemm<QKVC,  true ><<<dim3(MROWS/128, QKVC/128),  256, 0, stream>>>(enc_bf, wa_bf, attn_b, qkv);
  k_attn<<<dim3(SEQ/64, BATCH*NHEADS), 256, 0, stream>>>(qkv, aout);
  k_gemm<HIDDEN, false><<<dim3(MROWS/128, HIDDEN/128), 256, 0, stream>>>(aout, wo_bf, out_b, d_out);
}

// Round 2
// 144.683 us; speedup vs baseline: 1.3331x; 1.3331x over previous
//
#include <hip/hip_runtime.h>
#include <hip/hip_bf16.h>
#include <stdint.h>

#define HIDDEN 1024
#define NHEADS 16
#define DHEAD  64
#define BATCH  2
#define SEQ    2048
#define MROWS  (BATCH*SEQ)   // 4096
#define QKVC   (3*HIDDEN)    // 3072

typedef unsigned short u16;
typedef unsigned int   u32;
typedef __bf16 bf16x8 __attribute__((ext_vector_type(8)));
typedef float  f32x4  __attribute__((ext_vector_type(4)));
typedef short  s16x4  __attribute__((ext_vector_type(4)));
typedef u16    u16x8  __attribute__((ext_vector_type(8)));

typedef const __attribute__((address_space(1))) void gvoid_t;
typedef       __attribute__((address_space(3))) void lvoid_t;

__device__ __forceinline__ gvoid_t* to_glob(const void* p){
  return (gvoid_t*)(uintptr_t)p;
}
__device__ __forceinline__ lvoid_t* to_lds(void* p){
  return (lvoid_t*)(uintptr_t)p;
}
__device__ __forceinline__ u32 lds_off(const void* p){
  return (u32)(uintptr_t)p;
}

__device__ __forceinline__ u16 f2bf(float x){   // RNE f32->bf16
  u32 u = __builtin_bit_cast(u32, x);
  u32 r = (u + 0x7fffu + ((u >> 16) & 1u)) >> 16;
  return (u16)r;
}

// ---------------- fp32 -> bf16 conversion ----------------
__global__ __launch_bounds__(256) void k_cvt(const float* __restrict__ in,
                                             u16* __restrict__ out, int n4){
  int i = blockIdx.x * 256 + threadIdx.x;
  if (i >= n4) return;
  const float4 v = reinterpret_cast<const float4*>(in)[i];
  ushort4 o;
  o.x = f2bf(v.x); o.y = f2bf(v.y); o.z = f2bf(v.z); o.w = f2bf(v.w);
  reinterpret_cast<ushort4*>(out)[i] = o;
}

// ---------------- bf16 GEMM, C = A * B^T + bias ----------------
template<int NC, bool BF16OUT>
__global__ __launch_bounds__(256) void k_gemm(const u16* __restrict__ A,
                                              const u16* __restrict__ B,
                                              const float* __restrict__ bias,
                                              void* __restrict__ C){
  constexpr int K = HIDDEN;
  __shared__ u16 As[128*32];
  __shared__ u16 Bs[128*32];
  const int m0 = blockIdx.x * 128;
  const int n0 = blockIdx.y * 128;
  const int tid = threadIdx.x;
  const int w = tid >> 6, l = tid & 63;
  const int wr = w >> 1, wc = w & 1;

  const f32x4 fz = {0.f, 0.f, 0.f, 0.f};
  f32x4 acc[4][4];
  #pragma unroll
  for (int i = 0; i < 4; ++i)
    #pragma unroll
    for (int j = 0; j < 4; ++j) acc[i][j] = fz;

  const u16* ap = A + (size_t)(m0 + (tid >> 2)) * K + (tid & 3) * 8;
  const u16* bp = B + (size_t)(n0 + (tid >> 2)) * K + (tid & 3) * 8;

  for (int k0 = 0; k0 < K; k0 += 32){
    __syncthreads();
    __builtin_amdgcn_global_load_lds(to_glob(ap + k0),          to_lds(&As[w*512]),        16, 0, 0);
    __builtin_amdgcn_global_load_lds(to_glob(ap + 64*K + k0),   to_lds(&As[2048 + w*512]), 16, 0, 0);
    __builtin_amdgcn_global_load_lds(to_glob(bp + k0),          to_lds(&Bs[w*512]),        16, 0, 0);
    __builtin_amdgcn_global_load_lds(to_glob(bp + 64*K + k0),   to_lds(&Bs[2048 + w*512]), 16, 0, 0);
    __syncthreads();

    bf16x8 af[4], bfr[4];
    #pragma unroll
    for (int mf = 0; mf < 4; ++mf)
      af[mf]  = *(const bf16x8*)&As[(wr*64 + mf*16 + (l & 15))*32 + (l >> 4)*8];
    #pragma unroll
    for (int nf = 0; nf < 4; ++nf)
      bfr[nf] = *(const bf16x8*)&Bs[(wc*64 + nf*16 + (l & 15))*32 + (l >> 4)*8];
    #pragma unroll
    for (int mf = 0; mf < 4; ++mf)
      #pragma unroll
      for (int nf = 0; nf < 4; ++nf)
        acc[mf][nf] = __builtin_amdgcn_mfma_f32_16x16x32_bf16(af[mf], bfr[nf], acc[mf][nf], 0, 0, 0);
  }

  #pragma unroll
  for (int nf = 0; nf < 4; ++nf){
    const int col = n0 + wc*64 + nf*16 + (l & 15);
    const float bv = bias[col];
    #pragma unroll
    for (int mf = 0; mf < 4; ++mf){
      #pragma unroll
      for (int r = 0; r < 4; ++r){
        const int row = m0 + wr*64 + mf*16 + (l >> 4)*4 + r;
        const float v = acc[mf][nf][r] + bv;
        if constexpr (BF16OUT) ((u16*)C)[(size_t)row * NC + col] = f2bf(v);
        else                   ((float*)C)[(size_t)row * NC + col] = v;
      }
    }
  }
}

// ---------------- causal flash attention, paired q-tiles + dbuf ----------------
// grid = (BATCH*NHEADS, 16 pairs); block = 256 (4 waves, 16 q-rows/wave per q-tile).
// Block handles q-tiles {pair, 31-pair}: constant work, staged K/V shared by both.
// grid.x = head so all blocks of one head land on one XCD (linear id % 8 == head % 8).
__global__ __launch_bounds__(256) void k_attn(const u16* __restrict__ qkv,
                                              u16* __restrict__ aout){
  __shared__ u16 Ks[2][64*64];      // [buf][k][d], chunk-XOR swizzled
  __shared__ u16 Vs[2][64*64];      // [buf], subtiled for ds_read_b64_tr_b16
  __shared__ u16 Ps[4][32][72];     // [wave][tileSel*16+row][col], pad 72

  const int b   = blockIdx.x >> 4;
  const int h   = blockIdx.x & 15;
  const int qtA = blockIdx.y;        // 0..15
  const int qtB = 31 - qtA;          // 16..31
  const int tid = threadIdx.x;
  const int w = tid >> 6, l = tid & 63;
  const size_t base = (size_t)b * SEQ * QKVC + (size_t)h * 192;

  // Q fragments: A[row=q(l&15)][k=(l>>4)*8 + kk*32 + j]
  bf16x8 qfA[2], qfB[2];
  {
    const u16* qa = qkv + base + (size_t)(qtA*64 + w*16 + (l & 15)) * QKVC + (l >> 4) * 8;
    qfA[0] = *(const bf16x8*)(qa);  qfA[1] = *(const bf16x8*)(qa + 32);
    const u16* qb = qkv + base + (size_t)(qtB*64 + w*16 + (l & 15)) * QKVC + (l >> 4) * 8;
    qfB[0] = *(const bf16x8*)(qb);  qfB[1] = *(const bf16x8*)(qb + 32);
  }

  const f32x4 fz = {0.f, 0.f, 0.f, 0.f};
  f32x4 oA[4], oB[4];
  float mA[4], lA[4], mB[4], lB[4];
  #pragma unroll
  for (int i = 0; i < 4; ++i){
    oA[i] = fz; oB[i] = fz;
    mA[i] = -1e30f; mB[i] = -1e30f; lA[i] = 0.f; lB[i] = 0.f;
  }

  auto stageK = [&](int kt, int buf){
    #pragma unroll
    for (int t = 0; t < 2; ++t){
      const int i  = t*256 + tid;
      const int kr = i >> 3;
      const int cg = (i & 7) ^ (kr & 7);       // pre-swizzled global source (rule #21)
      const u16* src = qkv + base + (size_t)(kt*64 + kr) * QKVC + 64 + cg * 8;
      __builtin_amdgcn_global_load_lds(to_glob(src), to_lds(&Ks[buf][t*2048 + w*512]), 16, 0, 0);
    }
  };
  auto loadV = [&](int kt, u16x8* vt){
    #pragma unroll
    for (int t = 0; t < 2; ++t){
      const int i = t*256 + tid;
      const int k = i >> 3, d0 = (i & 7) * 8;
      vt[t] = *(const u16x8*)(qkv + base + (size_t)(kt*64 + k) * QKVC + 128 + d0);
    }
  };
  auto writeV = [&](int buf, const u16x8* vt){
    #pragma unroll
    for (int t = 0; t < 2; ++t){
      const int i = t*256 + tid;
      const int k = i >> 3, d0 = (i & 7) * 8;
      const int flat = ((k >> 5) << 11) + ((d0 >> 4) << 9) + (((k >> 2) & 1) << 8)
                     + (((k >> 3) & 3) << 6) + ((k & 3) << 4) + (d0 & 15);
      *(u16x8*)&Vs[buf][flat] = vt[t];
    }
  };

  // softmax + online rescale for one q-tile; writes P (bf16) to Ps[w][sel*16+..]
  auto softmax = [&](f32x4* s, float* mr, float* lr, f32x4* o, bool diag, int sel){
    float rmax[4] = {-1e30f, -1e30f, -1e30f, -1e30f};
    #pragma unroll
    for (int nf = 0; nf < 4; ++nf){
      #pragma unroll
      for (int r = 0; r < 4; ++r){
        float v = s[nf][r] * 0.125f;
        if (diag){
          const int qg = w*16 + ((l >> 4) << 2) + r;
          const int kg = nf*16 + (l & 15);
          if (kg > qg) v = -1e30f;
        }
        s[nf][r] = v;
        rmax[r] = fmaxf(rmax[r], v);
      }
    }
    #pragma unroll
    for (int r = 0; r < 4; ++r){
      #pragma unroll
      for (int msk = 1; msk < 16; msk <<= 1)
        rmax[r] = fmaxf(rmax[r], __shfl_xor(rmax[r], msk));
    }
    float corr[4], psum[4];
    #pragma unroll
    for (int r = 0; r < 4; ++r){
      const float mn = fmaxf(mr[r], rmax[r]);
      corr[r] = __expf(mr[r] - mn);
      mr[r] = mn;
      psum[r] = 0.f;
    }
    #pragma unroll
    for (int nf = 0; nf < 4; ++nf){
      #pragma unroll
      for (int r = 0; r < 4; ++r){
        const float p = __expf(s[nf][r] - mr[r]);
        psum[r] += p;
        Ps[w][sel*16 + ((l >> 4) << 2) + r][nf*16 + (l & 15)] = f2bf(p);
      }
    }
    #pragma unroll
    for (int r = 0; r < 4; ++r){
      #pragma unroll
      for (int msk = 1; msk < 16; msk <<= 1)
        psum[r] += __shfl_xor(psum[r], msk);
      lr[r] = lr[r] * corr[r] + psum[r];
    }
    #pragma unroll
    for (int nf = 0; nf < 4; ++nf)
      #pragma unroll
      for (int r = 0; r < 4; ++r)
        o[nf][r] *= corr[r];
  };

  // prologue: stage tile 0 into buf 0
  {
    u16x8 vt[2];
    stageK(0, 0);
    loadV(0, vt);
    writeV(0, vt);
  }
  __syncthreads();

  for (int kt = 0; kt <= qtB; ++kt){
    const int cur = kt & 1;
    const bool pf = (kt < qtB);
    u16x8 vt[2];
    if (pf){                       // prefetch next tile: K direct-to-LDS, V to regs
      stageK(kt + 1, cur ^ 1);
      loadV(kt + 1, vt);
    }
    const bool actA = (kt <= qtA);

    // ---- K fragments from Ks[cur] (shared B-operand for both q-tiles)
    bf16x8 kf[4][2];
    #pragma unroll
    for (int nf = 0; nf < 4; ++nf){
      const int row = nf*16 + (l & 15);
      const int sw  = row & 7;
      kf[nf][0] = *(const bf16x8*)&Ks[cur][row*64 + (((l >> 4)    ) ^ sw) * 8];
      kf[nf][1] = *(const bf16x8*)&Ks[cur][row*64 + (((l >> 4) + 4) ^ sw) * 8];
    }

    // ---- QK^T for both tiles
    f32x4 sB[4], sA[4];
    #pragma unroll
    for (int nf = 0; nf < 4; ++nf){
      f32x4 a = fz;
      a = __builtin_amdgcn_mfma_f32_16x16x32_bf16(qfB[0], kf[nf][0], a, 0, 0, 0);
      a = __builtin_amdgcn_mfma_f32_16x16x32_bf16(qfB[1], kf[nf][1], a, 0, 0, 0);
      sB[nf] = a;
    }
    if (actA){
      #pragma unroll
      for (int nf = 0; nf < 4; ++nf){
        f32x4 a = fz;
        a = __builtin_amdgcn_mfma_f32_16x16x32_bf16(qfA[0], kf[nf][0], a, 0, 0, 0);
        a = __builtin_amdgcn_mfma_f32_16x16x32_bf16(qfA[1], kf[nf][1], a, 0, 0, 0);
        sA[nf] = a;
      }
    }

    // ---- softmax (B always active; A while kt <= qtA)
    softmax(sB, mB, lB, oB, kt == qtB, 1);
    if (actA) softmax(sA, mA, lA, oA, kt == qtA, 0);

    // ---- PV: batched tr_reads, ONE wait per kk (V fragments shared by A and B)
    const u32 vb = lds_off(&Vs[cur][0]) + l * 8;
    #pragma unroll
    for (int kk = 0; kk < 2; ++kk){
      bf16x8 paB = *(const bf16x8*)&Ps[w][16 + (l & 15)][kk*32 + (l >> 4)*8];
      bf16x8 paA = paB;
      if (actA) paA = *(const bf16x8*)&Ps[w][(l & 15)][kk*32 + (l >> 4)*8];
      s16x4 t0,t1,t2,t3,t4,t5,t6,t7;
      const u32 va = vb + kk*4096;
      asm volatile("ds_read_b64_tr_b16 %0, %4 offset:0\n\t"
                   "ds_read_b64_tr_b16 %1, %4 offset:512\n\t"
                   "ds_read_b64_tr_b16 %2, %4 offset:1024\n\t"
                   "ds_read_b64_tr_b16 %3, %4 offset:1536"
                   : "=&v"(t0), "=&v"(t1), "=&v"(t2), "=&v"(t3) : "v"(va));
      asm volatile("ds_read_b64_tr_b16 %0, %4 offset:2048\n\t"
                   "ds_read_b64_tr_b16 %1, %4 offset:2560\n\t"
                   "ds_read_b64_tr_b16 %2, %4 offset:3072\n\t"
                   "ds_read_b64_tr_b16 %3, %4 offset:3584"
                   : "=&v"(t4), "=&v"(t5), "=&v"(t6), "=&v"(t7) : "v"(va));
      asm volatile("s_waitcnt lgkmcnt(0)" ::: "memory");
      __builtin_amdgcn_sched_barrier(0);
      union { s16x4 hh[2]; bf16x8 v; } c0, c1, c2, c3;
      c0.hh[0] = t0; c0.hh[1] = t1;
      c1.hh[0] = t2; c1.hh[1] = t3;
      c2.hh[0] = t4; c2.hh[1] = t5;
      c3.hh[0] = t6; c3.hh[1] = t7;
      oB[0] = __builtin_amdgcn_mfma_f32_16x16x32_bf16(paB, c0.v, oB[0], 0, 0, 0);
      oB[1] = __builtin_amdgcn_mfma_f32_16x16x32_bf16(paB, c1.v, oB[1], 0, 0, 0);
      oB[2] = __builtin_amdgcn_mfma_f32_16x16x32_bf16(paB, c2.v, oB[2], 0, 0, 0);
      oB[3] = __builtin_amdgcn_mfma_f32_16x16x32_bf16(paB, c3.v, oB[3], 0, 0, 0);
      if (actA){
        oA[0] = __builtin_amdgcn_mfma_f32_16x16x32_bf16(paA, c0.v, oA[0], 0, 0, 0);
        oA[1] = __builtin_amdgcn_mfma_f32_16x16x32_bf16(paA, c1.v, oA[1], 0, 0, 0);
        oA[2] = __builtin_amdgcn_mfma_f32_16x16x32_bf16(paA, c2.v, oA[2], 0, 0, 0);
        oA[3] = __builtin_amdgcn_mfma_f32_16x16x32_bf16(paA, c3.v, oA[3], 0, 0, 0);
      }
    }

    if (pf) writeV(cur ^ 1, vt);   // deps force vmcnt wait for V regs here
    __syncthreads();               // next-tile K (vmcnt drained) + V visible; cur reads done
  }

  // ---- epilogue: normalize, write bf16 [token][h*64+d]
  auto epi = [&](const f32x4* o, const float* lr, int qt){
    #pragma unroll
    for (int r = 0; r < 4; ++r){
      const float inv = 1.0f / lr[r];
      const int qg = qt*64 + w*16 + ((l >> 4) << 2) + r;
      u16* op = aout + (size_t)(b*SEQ + qg) * HIDDEN + h*64 + (l & 15);
      #pragma unroll
      for (int nf = 0; nf < 4; ++nf)
        op[nf*16] = f2bf(o[nf][r] * inv);
    }
  };
  epi(oA, lA, qtA);
  epi(oB, lB, qtB);
}

// ---------------- launch ----------------
extern "C" void kernel_launch(void* const* d_in, const int* in_sizes, int n_in,
                              void* d_out, int out_size, void* d_ws, size_t ws_size,
                              hipStream_t stream){
  const float* enc    = (const float*)d_in[0];
  const float* attn_w = (const float*)d_in[1];
  const float* attn_b = (const float*)d_in[2];
  const float* out_w  = (const float*)d_in[3];
  const float* out_b  = (const float*)d_in[4];

  char* ws = (char*)d_ws;
  u16* enc_bf = (u16*)(ws);
  u16* wa_bf  = (u16*)(ws + (size_t)( 8u << 20));
  u16* wo_bf  = (u16*)(ws + (size_t)(14u << 20));
  u16* qkv    = (u16*)(ws + (size_t)(16u << 20));
  u16* aout   = enc_bf;  // safe alias: attn runs strictly after GEMM1

  k_cvt<<<dim3((MROWS*HIDDEN/4 + 255)/256), 256, 0, stream>>>(enc,    enc_bf, MROWS*HIDDEN/4);
  k_cvt<<<dim3((QKVC*HIDDEN/4  + 255)/256), 256, 0, stream>>>(attn_w, wa_bf,  QKVC*HIDDEN/4);
  k_cvt<<<dim3((HIDDEN*HIDDEN/4+ 255)/256), 256, 0, stream>>>(out_w,  wo_bf,  HIDDEN*HIDDEN/4);

  k_gemm<QKVC,  true ><<<dim3(MROWS/128, QKVC/128),  256, 0, stream>>>(enc_bf, wa_bf, attn_b, qkv);
  k_attn<<<dim3(BATCH*NHEADS, 16), 256, 0, stream>>>(qkv, aout);
  k_gemm<HIDDEN, false><<<dim3(MROWS/128, HIDDEN/128), 256, 0, stream>>>(aout, wo_bf, out_b, d_out);
}